// Round 11
// baseline (99.727 us; speedup 1.0000x reference)
//
#include <hip/hip_runtime.h>
#include <hip/hip_fp16.h>
#include <math.h>

// Problem constants: B=8, T=64, R=100, TH=768, IH=1024, P=N=512
#define B_  8
#define T_  64
#define R_  100
#define TH_ 768
#define IH_ 1024
#define P_  512
#define N_  512

#define CTANH 2.88539008177792681f   // 2*log2(e): tanh(x) = 1 - 2/(1+exp2(CTANH*x))
#define PADK2 72                     // 64 k-elems + 8 pad (stride 144 B, 2-way max)

typedef short short8  __attribute__((ext_vector_type(8)));
typedef float floatx4 __attribute__((ext_vector_type(4)));

__device__ __forceinline__ ushort f2bf(float f) {
  union { float f; unsigned int u; } v; v.f = f;
  unsigned int r = v.u + 0x7FFFu + ((v.u >> 16) & 1u);   // RNE
  return (ushort)(r >> 16);
}

// ---------------------------------------------------------------------------
// MFMA bf16 GEMM + bias + exact GELU -> f16 (pre-scaled by CTANH).
// In-block split-K=4, BK=64 per split (was 32): 1024 thr = 4 splits x 4 waves,
// tile 64m x 32n, grid (16,21) = 336 blocks (all co-resident, 2/CU).
// K-loop iterations: 3 (Q) / 4 (K) — half of R6's sk4; per iter 4 global
// loads + 6 ds_read_b128 + 4 MFMA in flight. Targets the barrier-delimited
// serial chain that made sk4 ~18 us.
// ---------------------------------------------------------------------------
__global__ __launch_bounds__(1024) void mfma_linear_gelu_sk4b(
    const float* __restrict__ encT, const float* __restrict__ Wq,
    const float* __restrict__ bq, __half* __restrict__ qout,
    const float* __restrict__ encI, const float* __restrict__ Wk,
    const float* __restrict__ bk, __half* __restrict__ kout) {
  const int rt = blockIdx.y;
  const bool isQ = rt < 8;
  const float* __restrict__ X = isQ ? encT : encI;
  const float* __restrict__ W = isQ ? Wq : Wk;
  const float* __restrict__ bias = isQ ? bq : bk;
  __half* __restrict__ Y = isQ ? qout : kout;
  const int M    = isQ ? (B_ * T_) : (B_ * R_);
  const int KDIM = isQ ? TH_ : IH_;
  const int row0 = (isQ ? rt : (rt - 8)) * 64;
  const int col0 = blockIdx.x * 32;
  const int kq   = KDIM >> 2;              // k-quarter: 192 or 256
  const int ntiles = kq >> 6;              // 3 (Q) or 4 (K)

  __shared__ ushort As[4][64 * PADK2];     // 36864 B
  __shared__ ushort Bs[4][32 * PADK2];     // 18432 B
  __shared__ float  red[2][64 * 33];       // 16896 B  -> 72192 B total

  const int tid = threadIdx.x;
  const int sp  = tid >> 8;                // split 0..3
  const int t   = tid & 255;
  const int kbase = sp * kq;

  // A loader: row t>>2 (0..63), k-chunk (t&3)*16 .. +15
  const int arow = t >> 2;
  const int ak16 = (t & 3) * 16;
  const int arowc = min(row0 + arow, M - 1);
  const float* __restrict__ Xp = X + (size_t)arowc * KDIM + kbase + ak16;

  // B loader: k-quad (t>>4)*4, col-pair (t&15)*2
  const int bk4 = (t >> 4) * 4;
  const int bn2 = (t & 15) * 2;
  const float* __restrict__ Wp = W + (size_t)(kbase + bk4) * N_ + col0 + bn2;

  // compute mapping: wave covers 16 rows x 32 cols
  const int wv = t >> 6;
  const int lane = t & 63;
  const int wm = wv * 16;
  const int l15 = lane & 15;
  const int q8  = (lane >> 4) * 8;
  const int q4  = (lane >> 4) * 4;

  floatx4 acc0 = {0.f,0.f,0.f,0.f}, acc1 = {0.f,0.f,0.f,0.f};

  float4 a0 = *(const float4*)(Xp);
  float4 a1 = *(const float4*)(Xp + 4);
  float4 a2 = *(const float4*)(Xp + 8);
  float4 a3 = *(const float4*)(Xp + 12);
  float2 b0 = *(const float2*)(Wp);
  float2 b1 = *(const float2*)(Wp + N_);
  float2 b2 = *(const float2*)(Wp + 2 * N_);
  float2 b3 = *(const float2*)(Wp + 3 * N_);

  for (int kt = 0; kt < ntiles; ++kt) {
    {
      short8 p0, p1;
      p0[0] = (short)f2bf(a0.x); p0[1] = (short)f2bf(a0.y);
      p0[2] = (short)f2bf(a0.z); p0[3] = (short)f2bf(a0.w);
      p0[4] = (short)f2bf(a1.x); p0[5] = (short)f2bf(a1.y);
      p0[6] = (short)f2bf(a1.z); p0[7] = (short)f2bf(a1.w);
      p1[0] = (short)f2bf(a2.x); p1[1] = (short)f2bf(a2.y);
      p1[2] = (short)f2bf(a2.z); p1[3] = (short)f2bf(a2.w);
      p1[4] = (short)f2bf(a3.x); p1[5] = (short)f2bf(a3.y);
      p1[6] = (short)f2bf(a3.z); p1[7] = (short)f2bf(a3.w);
      *(short8*)&As[sp][arow * PADK2 + ak16]     = p0;
      *(short8*)&As[sp][arow * PADK2 + ak16 + 8] = p1;
    }
    {
      unsigned int c00 = (unsigned int)f2bf(b0.x) | ((unsigned int)f2bf(b1.x) << 16);
      unsigned int c01 = (unsigned int)f2bf(b2.x) | ((unsigned int)f2bf(b3.x) << 16);
      unsigned int c10 = (unsigned int)f2bf(b0.y) | ((unsigned int)f2bf(b1.y) << 16);
      unsigned int c11 = (unsigned int)f2bf(b2.y) | ((unsigned int)f2bf(b3.y) << 16);
      *(unsigned int*)&Bs[sp][(bn2 + 0) * PADK2 + bk4]     = c00;
      *(unsigned int*)&Bs[sp][(bn2 + 0) * PADK2 + bk4 + 2] = c01;
      *(unsigned int*)&Bs[sp][(bn2 + 1) * PADK2 + bk4]     = c10;
      *(unsigned int*)&Bs[sp][(bn2 + 1) * PADK2 + bk4 + 2] = c11;
    }
    __syncthreads();

    if (kt + 1 < ntiles) {
      const int kb = (kt + 1) * 64;
      a0 = *(const float4*)(Xp + kb);
      a1 = *(const float4*)(Xp + kb + 4);
      a2 = *(const float4*)(Xp + kb + 8);
      a3 = *(const float4*)(Xp + kb + 12);
      b0 = *(const float2*)(Wp + (size_t)kb * N_);
      b1 = *(const float2*)(Wp + (size_t)(kb + 1) * N_);
      b2 = *(const float2*)(Wp + (size_t)(kb + 2) * N_);
      b3 = *(const float2*)(Wp + (size_t)(kb + 3) * N_);
    }

    short8 afA  = *(const short8*)&As[sp][(wm + l15) * PADK2 + q8];
    short8 afB  = *(const short8*)&As[sp][(wm + l15) * PADK2 + 32 + q8];
    short8 bf0A = *(const short8*)&Bs[sp][(l15) * PADK2 + q8];
    short8 bf0B = *(const short8*)&Bs[sp][(l15) * PADK2 + 32 + q8];
    short8 bf1A = *(const short8*)&Bs[sp][(16 + l15) * PADK2 + q8];
    short8 bf1B = *(const short8*)&Bs[sp][(16 + l15) * PADK2 + 32 + q8];
    acc0 = __builtin_amdgcn_mfma_f32_16x16x32_bf16(afA, bf0A, acc0, 0, 0, 0);
    acc1 = __builtin_amdgcn_mfma_f32_16x16x32_bf16(afA, bf1A, acc1, 0, 0, 0);
    acc0 = __builtin_amdgcn_mfma_f32_16x16x32_bf16(afB, bf0B, acc0, 0, 0, 0);
    acc1 = __builtin_amdgcn_mfma_f32_16x16x32_bf16(afB, bf1B, acc1, 0, 0, 0);
    __syncthreads();
  }

  // cross-split tree reduce (unchanged from sk4)
  if (sp >= 2) {
    float* L = red[sp - 2];
    #pragma unroll
    for (int j = 0; j < 4; ++j) {
      L[(wm + q4 + j) * 33 + l15]      = acc0[j];
      L[(wm + q4 + j) * 33 + 16 + l15] = acc1[j];
    }
  }
  __syncthreads();
  if (sp < 2) {
    const float* L = red[sp];
    #pragma unroll
    for (int j = 0; j < 4; ++j) {
      acc0[j] += L[(wm + q4 + j) * 33 + l15];
      acc1[j] += L[(wm + q4 + j) * 33 + 16 + l15];
    }
  }
  __syncthreads();
  if (sp == 1) {
    float* L = red[0];
    #pragma unroll
    for (int j = 0; j < 4; ++j) {
      L[(wm + q4 + j) * 33 + l15]      = acc0[j];
      L[(wm + q4 + j) * 33 + 16 + l15] = acc1[j];
    }
  }
  __syncthreads();
  if (sp == 0) {
    const float* L = red[0];
    const float is2 = 0.70710678118654752f;
    const float bia0 = bias[col0 + l15];
    const float bia1 = bias[col0 + 16 + l15];
    #pragma unroll
    for (int j = 0; j < 4; ++j) {
      const int row = row0 + wm + q4 + j;
      if (row < M) {
        float v0 = acc0[j] + L[(wm + q4 + j) * 33 + l15] + bia0;
        float v1 = acc1[j] + L[(wm + q4 + j) * 33 + 16 + l15] + bia1;
        v0 = CTANH * 0.5f * v0 * (1.f + erff(v0 * is2));
        v1 = CTANH * 0.5f * v1 * (1.f + erff(v1 * is2));
        Y[(size_t)row * N_ + col0 + l15]      = __float2half(v0);
        Y[(size_t)row * N_ + col0 + 16 + l15] = __float2half(v1);
      }
    }
  }
}

// ---------------------------------------------------------------------------
// Fusion — BYTE-IDENTICAL to round 6's fuse_kernel_h (best measured: ~11 us).
// One wave = one rg (4 r's, 16 lanes each, 32 p/lane). Grid (512, 7).
// ---------------------------------------------------------------------------
__global__ __launch_bounds__(256) void fuse_kernel_h(
    const __half* __restrict__ q, const __half* __restrict__ k,
    const float* __restrict__ w, const float* __restrict__ bscalar,
    const float* __restrict__ mask, float* __restrict__ out) {
  const int bt = blockIdx.x;               // 0..511
  const int wave = threadIdx.x >> 6;
  const int rg = blockIdx.y * 4 + wave;    // 0..27
  if (rg >= 25) return;                    // whole-wave exit; no barriers used
  const int lane = threadIdx.x & 63;
  const int sub  = lane >> 4;              // r within group of 4
  const int pi   = lane & 15;              // p-slice
  const int r = rg * 4 + sub;              // 0..99
  const int b = bt >> 6;

  const __half* __restrict__ qp = q + (size_t)bt * P_ + pi * 8;
  const __half* __restrict__ kp = k + (size_t)(b * R_ + r) * P_ + pi * 8;
  const float* __restrict__ wp = w + pi * 8;

  float acc0 = 0.f, acc1 = 0.f;
  #pragma unroll
  for (int i = 0; i < 4; ++i) {
    union { float4 f; __half2 h[4]; } qu, ku;
    qu.f = *(const float4*)(qp + i * 128);
    ku.f = *(const float4*)(kp + i * 128);
    float4 w0 = *(const float4*)(wp + i * 128);
    float4 w1 = *(const float4*)(wp + i * 128 + 4);
    #pragma unroll
    for (int e = 0; e < 4; ++e) {
      __half2 s = __hadd2(qu.h[e], ku.h[e]);
      float x0 = __low2float(s);
      float x1 = __high2float(s);
      float d0 = __builtin_amdgcn_rcpf(1.f + __builtin_amdgcn_exp2f(x0));
      float d1 = __builtin_amdgcn_rcpf(1.f + __builtin_amdgcn_exp2f(x1));
      float s0 = fmaf(-2.f, d0, 1.f);
      float s1 = fmaf(-2.f, d1, 1.f);
      const float we0 = (e == 0) ? w0.x : (e == 1) ? w0.z : (e == 2) ? w1.x : w1.z;
      const float we1 = (e == 0) ? w0.y : (e == 1) ? w0.w : (e == 2) ? w1.y : w1.w;
      acc0 = fmaf(we0, s0, acc0);
      acc1 = fmaf(we1, s1, acc1);
    }
  }
  float acc = acc0 + acc1;
  #pragma unroll
  for (int off = 1; off < 16; off <<= 1) acc += __shfl_xor(acc, off, 64);

  if (pi == 0) {
    out[(size_t)bt * R_ + r] = acc + bscalar[0] + mask[(size_t)bt * R_ + r];
  }
}

// ---------------------------------------------------------------------------
extern "C" void kernel_launch(void* const* d_in, const int* in_sizes, int n_in,
                              void* d_out, int out_size, void* d_ws, size_t ws_size,
                              hipStream_t stream) {
  const float* encT = (const float*)d_in[0];
  const float* encI = (const float*)d_in[1];
  const float* mask = (const float*)d_in[2];
  const float* Wq   = (const float*)d_in[3];
  const float* bq   = (const float*)d_in[4];
  const float* Wk   = (const float*)d_in[5];
  const float* bk   = (const float*)d_in[6];
  const float* w    = (const float*)d_in[7];
  const float* bsc  = (const float*)d_in[8];
  float* out = (float*)d_out;

  __half* q = (__half*)d_ws;               // [512, 512] f16, CTANH-prescaled
  __half* k = q + (size_t)B_ * T_ * P_;    // [800, 512] f16, CTANH-prescaled

  dim3 grid(N_ / 32, 8 + 13);              // 336 blocks x 1024 threads
  mfma_linear_gelu_sk4b<<<grid, 1024, 0, stream>>>(encT, Wq, bq, q,
                                                   encI, Wk, bk, k);

  fuse_kernel_h<<<dim3(512, 7), 256, 0, stream>>>(q, k, w, bsc, mask, out);
}